// Round 1
// baseline (365.184 us; speedup 1.0000x reference)
//
#include <hip/hip_runtime.h>

// NaryDecoderCell: B=2048, C=256, HS=512, H2=1024, D=8
// Pipeline: pack(bf16 casts) -> GEMM gi -> GEMM gh -> GRU pointwise (+probs)
//           -> split-K GEMM hc -> reduce+tanh -> h
// Workspace assumed >= 345 MB.

#define B_   2048
#define C_   256
#define HS_  512
#define H2_  1024
#define G3_  3072          // 3*H2
#define D_   8
#define NG_  24576         // D*3*H2

typedef __attribute__((ext_vector_type(8))) short bfrag;   // 8 x bf16 (4 VGPR)
typedef __attribute__((ext_vector_type(4))) float f32x4;   // MFMA C/D

static __device__ __forceinline__ unsigned short f2bf(float f) {
  unsigned u = __float_as_uint(f);
  u = (u + 0x7FFFu + ((u >> 16) & 1u)) >> 16;   // RTNE
  return (unsigned short)u;
}
static __device__ __forceinline__ float bf2f(unsigned short s) {
  return __uint_as_float(((unsigned)s) << 16);
}
static __device__ __forceinline__ float fast_sigmoid(float x) {
  return 1.f / (1.f + __expf(-x));
}
static __device__ __forceinline__ float fast_tanh(float x) {
  // 1 - 2/(e^{2x}+1); saturates correctly for |x| large
  return 1.f - 2.f / (__expf(2.f * x) + 1.f);
}

__device__ __forceinline__ void load16(const void* g, void* l) {
  __builtin_amdgcn_global_load_lds((const __attribute__((address_space(1))) void*)g,
                                   (__attribute__((address_space(3))) void*)l,
                                   16, 0, 0);
}

// ---------------- pack: f32 -> bf16 casts/permutes ----------------
// ranges (element idx): A1 [0,524288) | A2 [..,2621440) | Wih [..,8912896)
//                       Whh [..,34078720) | WhBt [..,38273024)
__global__ __launch_bounds__(256) void pack_kernel(
    const float* __restrict__ x, const float* __restrict__ ph,
    const float* __restrict__ enc, const float* __restrict__ Wih,
    const float* __restrict__ Whh, const float* __restrict__ Wh,
    unsigned short* __restrict__ A1, unsigned short* __restrict__ A2,
    unsigned short* __restrict__ BWih, unsigned short* __restrict__ BWhh,
    unsigned short* __restrict__ BWh)
{
  const long long total4 = 38273024LL / 4;
  const long long stride = (long long)gridDim.x * blockDim.x;
  for (long long i = (long long)blockIdx.x * blockDim.x + threadIdx.x;
       i < total4; i += stride) {
    long long o = i * 4;
    float4 v;
    unsigned short* dst;
    if (o < 524288) {                       // A1 = x (flat cast)
      v = *(const float4*)(x + o);
      dst = A1 + o;
    } else if (o < 2621440) {               // A2 = [parent_h | encoding]
      long long rel = o - 524288;
      int b = (int)(rel >> 10), c = (int)(rel & 1023);
      const float* src = (c < 512) ? (ph + b * 512 + c) : (enc + b * 512 + (c - 512));
      v = *(const float4*)src;
      dst = A2 + rel;
    } else if (o < 8912896) {               // W_ih flat [24576][256]
      long long rel = o - 2621440;
      v = *(const float4*)(Wih + rel);
      dst = BWih + rel;
    } else if (o < 34078720) {              // W_hh flat [24576][1024]
      long long rel = o - 8912896;
      v = *(const float4*)(Whh + rel);
      dst = BWhh + rel;
    } else {                                // W_h permute -> Bt[kk][d*1024+h]
      long long rel = o - 34078720;
      int kk = (int)(rel >> 13);
      int r2 = (int)(rel & 8191);
      int d = r2 >> 10, hh = r2 & 1023;
      v = *(const float4*)(Wh + ((long long)d * 524288 + kk * 1024 + hh));
      dst = BWh + rel;
    }
    ushort4 w;
    w.x = f2bf(v.x); w.y = f2bf(v.y); w.z = f2bf(v.z); w.w = f2bf(v.w);
    *(ushort4*)dst = w;
  }
}

// ---------------- GEMM: C[M,N] = A[M,K] * Bt[N,K]^T  (bf16 in, f32 acc) ----
// 128x128 tile, 4 waves (2x2), BK=32, m97 2-barrier structure.
__global__ __launch_bounds__(256) void gemm_bt(
    const unsigned short* __restrict__ A, const unsigned short* __restrict__ Bt,
    void* __restrict__ out, int M, int N, int K, int kPerSlice, int outF32)
{
  __shared__ unsigned short sA[128 * 32];
  __shared__ unsigned short sB[128 * 32];
  const int t = threadIdx.x;
  const int wave = t >> 6, lane = t & 63;
  const int wr = wave >> 1, wc = wave & 1;
  const int brow = blockIdx.y << 7;
  const int bcol = blockIdx.x << 7;
  const int kOff = blockIdx.z * kPerSlice;

  f32x4 acc[4][4];
#pragma unroll
  for (int m = 0; m < 4; m++)
#pragma unroll
    for (int n = 0; n < 4; n++) acc[m][n] = (f32x4){0.f, 0.f, 0.f, 0.f};

  const int srow = t >> 2;              // 0..63
  const int scol = (t & 3) << 3;        // 0,8,16,24
  const unsigned short* aSrc = A + (size_t)(brow + srow) * K + kOff + scol;
  const unsigned short* bSrc = Bt + (size_t)(bcol + srow) * K + kOff + scol;
  const size_t rowStep = (size_t)64 * K;
  unsigned short* dA0 = sA + wave * 512;
  unsigned short* dA1 = sA + 2048 + wave * 512;
  unsigned short* dB0 = sB + wave * 512;
  unsigned short* dB1 = sB + 2048 + wave * 512;

  const int la = lane & 15;
  const int lk = (lane >> 4) << 3;
  const int kSteps = kPerSlice >> 5;

  for (int ks = 0; ks < kSteps; ++ks) {
    load16(aSrc, dA0);
    load16(aSrc + rowStep, dA1);
    load16(bSrc, dB0);
    load16(bSrc + rowStep, dB1);
    aSrc += 32; bSrc += 32;
    __syncthreads();                     // vmcnt(0) drain -> tiles ready
    bfrag aF[4], bF[4];
#pragma unroll
    for (int m = 0; m < 4; m++)
      aF[m] = *(const bfrag*)&sA[(wr * 64 + m * 16 + la) * 32 + lk];
#pragma unroll
    for (int n = 0; n < 4; n++)
      bF[n] = *(const bfrag*)&sB[(wc * 64 + n * 16 + la) * 32 + lk];
#pragma unroll
    for (int m = 0; m < 4; m++)
#pragma unroll
      for (int n = 0; n < 4; n++)
        acc[m][n] = __builtin_amdgcn_mfma_f32_16x16x32_bf16(aF[m], bF[n], acc[m][n], 0, 0, 0);
    __syncthreads();                     // protect LDS before next stage
  }

  // epilogue: D row=(lane>>4)*4+r, col=lane&15 within each 16x16 frag
  const int orow = brow + wr * 64 + (lane >> 4) * 4;
  const int ocol = bcol + wc * 64 + la;
  if (outF32) {
    float* o = (float*)out + (size_t)blockIdx.z * ((size_t)M * N);
#pragma unroll
    for (int m = 0; m < 4; m++) {
      const int rb = orow + m * 16;
#pragma unroll
      for (int n = 0; n < 4; n++) {
        const int cb = ocol + n * 16;
#pragma unroll
        for (int r = 0; r < 4; r++)
          o[(size_t)(rb + r) * N + cb] = acc[m][n][r];
      }
    }
  } else {
    unsigned short* o = (unsigned short*)out;
#pragma unroll
    for (int m = 0; m < 4; m++) {
      const int rb = orow + m * 16;
#pragma unroll
      for (int n = 0; n < 4; n++) {
        const int cb = ocol + n * 16;
#pragma unroll
        for (int r = 0; r < 4; r++)
          o[(size_t)(rb + r) * N + cb] = f2bf(acc[m][n][r]);
      }
    }
  }
}

// ---------------- GRU pointwise + probs ----------------
// one block per (b,d); 256 threads x 4 h-elems
__global__ __launch_bounds__(256) void gru_pointwise(
    const unsigned short* __restrict__ Gi, const unsigned short* __restrict__ Gh,
    const float* __restrict__ b_ih, const float* __restrict__ b_hh,
    const float* __restrict__ ph, const float* __restrict__ enc,
    const float* __restrict__ W_p, const float* __restrict__ b_p,
    unsigned short* __restrict__ hn, float* __restrict__ probs)
{
  const int bd = blockIdx.x;
  const int b = bd >> 3, d = bd & 7;
  const int t = threadIdx.x;
  const size_t gbase = (size_t)b * NG_ + (size_t)d * G3_;
  const int bbase = d * G3_;
  float partial = 0.f;
#pragma unroll
  for (int i = 0; i < 4; ++i) {
    const int h = t + (i << 8);
    float ir  = bf2f(Gi[gbase + h])        + b_ih[bbase + h];
    float iz  = bf2f(Gi[gbase + 1024 + h]) + b_ih[bbase + 1024 + h];
    float inn = bf2f(Gi[gbase + 2048 + h]) + b_ih[bbase + 2048 + h];
    float hr  = bf2f(Gh[gbase + h])        + b_hh[bbase + h];
    float hz  = bf2f(Gh[gbase + 1024 + h]) + b_hh[bbase + 1024 + h];
    float hnn = bf2f(Gh[gbase + 2048 + h]) + b_hh[bbase + 2048 + h];
    float r = fast_sigmoid(ir + hr);
    float z = fast_sigmoid(iz + hz);
    float nn = fast_tanh(inn + r * hnn);
    float h0 = (h < 512) ? ph[b * 512 + h] : enc[b * 512 + h - 512];
    float hv = (1.f - z) * nn + z * h0;
    hn[(size_t)b * 8192 + d * 1024 + h] = f2bf(hv);
    partial += hv * W_p[d * 1024 + h];
  }
  __shared__ float red[256];
  red[t] = partial;
  __syncthreads();
  for (int s = 128; s > 0; s >>= 1) {
    if (t < s) red[t] += red[t + s];
    __syncthreads();
  }
  if (t == 0) probs[bd] = fast_sigmoid(red[0] + b_p[d]);
}

// ---------------- reduce split-K partials + bias + tanh -> h ----------------
__global__ __launch_bounds__(256) void reduce_h_kernel(
    const float* __restrict__ part, const float* __restrict__ b_h,
    float* __restrict__ hout)
{
  const int idx = blockIdx.x * 256 + threadIdx.x;   // grid covers 2048*512 exactly
  const int kk = idx & 511;
  float s = 0.f;
#pragma unroll
  for (int sl = 0; sl < 8; ++sl) s += part[(size_t)sl * 1048576 + idx];
  float bias = 0.f;
#pragma unroll
  for (int d = 0; d < 8; ++d) bias += b_h[d * 512 + kk];
  hout[idx] = fast_tanh(s + bias);
}

extern "C" void kernel_launch(void* const* d_in, const int* in_sizes, int n_in,
                              void* d_out, int out_size, void* d_ws, size_t ws_size,
                              hipStream_t stream) {
  const float* x   = (const float*)d_in[0];
  const float* ph  = (const float*)d_in[1];
  const float* enc = (const float*)d_in[2];
  const float* Wih = (const float*)d_in[3];
  const float* Whh = (const float*)d_in[4];
  const float* bih = (const float*)d_in[5];
  const float* bhh = (const float*)d_in[6];
  const float* Wp  = (const float*)d_in[7];
  const float* bp  = (const float*)d_in[8];
  const float* Wh  = (const float*)d_in[9];
  const float* bh  = (const float*)d_in[10];
  float* out = (float*)d_out;
  char* ws = (char*)d_ws;

  unsigned short* A1   = (unsigned short*)(ws + 0);          // 1 MB
  unsigned short* A2   = (unsigned short*)(ws + 1048576);    // 4 MB
  unsigned short* BWih = (unsigned short*)(ws + 5242880);    // 12.6 MB
  unsigned short* BWhh = (unsigned short*)(ws + 17825792);   // 50.3 MB
  unsigned short* BWh  = (unsigned short*)(ws + 68157440);   // 8.4 MB
  unsigned short* Gi   = (unsigned short*)(ws + 76546048);   // 100.7 MB
  unsigned short* Gh   = (unsigned short*)(ws + 177209344);  // 100.7 MB
  unsigned short* hn   = (unsigned short*)(ws + 277872640);  // 33.6 MB
  float*          part = (float*)(ws + 311427072);           // 33.6 MB (8 slices)

  pack_kernel<<<2048, 256, 0, stream>>>(x, ph, enc, Wih, Whh, Wh,
                                        A1, A2, BWih, BWhh, BWh);

  dim3 g1(NG_ / 128, B_ / 128, 1);                 // (192,16)
  gemm_bt<<<g1, 256, 0, stream>>>(A1, BWih, Gi, B_, NG_, C_, C_, 0);
  gemm_bt<<<g1, 256, 0, stream>>>(A2, BWhh, Gh, B_, NG_, H2_, H2_, 0);

  gru_pointwise<<<B_ * D_, 256, 0, stream>>>(Gi, Gh, bih, bhh, ph, enc, Wp, bp,
                                             hn, out + 1048576);

  dim3 g3(HS_ / 128, B_ / 128, 8);                 // (4,16,8) split-K
  gemm_bt<<<g3, 256, 0, stream>>>(hn, BWh, part, B_, HS_, 8192, 1024, 1);

  reduce_h_kernel<<<4096, 256, 0, stream>>>(part, bh, out);
}

// Round 2
// 307.996 us; speedup vs baseline: 1.1857x; 1.1857x over previous
//
#include <hip/hip_runtime.h>

// NaryDecoderCell: B=2048, C=256, HS=512, H2=1024, D=8
// pack(bf16) -> gemm256(gi) -> gemm256(gh) -> GRU pointwise (+probs)
//            -> split-K gemm_bt(hc) -> reduce+tanh -> h

#define B_   2048
#define C_   256
#define HS_  512
#define H2_  1024
#define G3_  3072
#define D_   8
#define NG_  24576

typedef __attribute__((ext_vector_type(8))) short bfrag;   // 8 x bf16
typedef __attribute__((ext_vector_type(4))) float f32x4;   // MFMA C/D

static __device__ __forceinline__ unsigned short f2bf(float f) {
  unsigned u = __float_as_uint(f);
  u = (u + 0x7FFFu + ((u >> 16) & 1u)) >> 16;   // RTNE
  return (unsigned short)u;
}
static __device__ __forceinline__ float bf2f(unsigned short s) {
  return __uint_as_float(((unsigned)s) << 16);
}
static __device__ __forceinline__ float fast_sigmoid(float x) {
  return 1.f / (1.f + __expf(-x));
}
static __device__ __forceinline__ float fast_tanh(float x) {
  return 1.f - 2.f / (__expf(2.f * x) + 1.f);
}

__device__ __forceinline__ void load16(const void* g, void* l) {
  __builtin_amdgcn_global_load_lds((const __attribute__((address_space(1))) void*)g,
                                   (__attribute__((address_space(3))) void*)l,
                                   16, 0, 0);
}

// ---------------- pack: f32 -> bf16 casts/permutes ----------------
__global__ __launch_bounds__(256) void pack_kernel(
    const float* __restrict__ x, const float* __restrict__ ph,
    const float* __restrict__ enc, const float* __restrict__ Wih,
    const float* __restrict__ Whh, const float* __restrict__ Wh,
    unsigned short* __restrict__ A1, unsigned short* __restrict__ A2,
    unsigned short* __restrict__ BWih, unsigned short* __restrict__ BWhh,
    unsigned short* __restrict__ BWh)
{
  const long long total4 = 38273024LL / 4;
  const long long stride = (long long)gridDim.x * blockDim.x;
  for (long long i = (long long)blockIdx.x * blockDim.x + threadIdx.x;
       i < total4; i += stride) {
    long long o = i * 4;
    float4 v;
    unsigned short* dst;
    if (o < 524288) {
      v = *(const float4*)(x + o);
      dst = A1 + o;
    } else if (o < 2621440) {
      long long rel = o - 524288;
      int b = (int)(rel >> 10), c = (int)(rel & 1023);
      const float* src = (c < 512) ? (ph + b * 512 + c) : (enc + b * 512 + (c - 512));
      v = *(const float4*)src;
      dst = A2 + rel;
    } else if (o < 8912896) {
      long long rel = o - 2621440;
      v = *(const float4*)(Wih + rel);
      dst = BWih + rel;
    } else if (o < 34078720) {
      long long rel = o - 8912896;
      v = *(const float4*)(Whh + rel);
      dst = BWhh + rel;
    } else {
      long long rel = o - 34078720;
      int kk = (int)(rel >> 13);
      int r2 = (int)(rel & 8191);
      int d = r2 >> 10, hh = r2 & 1023;
      v = *(const float4*)(Wh + ((long long)d * 524288 + kk * 1024 + hh));
      dst = BWh + rel;
    }
    ushort4 w;
    w.x = f2bf(v.x); w.y = f2bf(v.y); w.z = f2bf(v.z); w.w = f2bf(v.w);
    *(ushort4*)dst = w;
  }
}

// ---------------- 256x256 8-phase GEMM: C[M,N] = A[M,K] * Bt[N,K]^T --------
// 8 waves (2M x 4N), BK=64, 128 KiB dynamic LDS double-buffer,
// counted vmcnt(4), XOR-swizzled LDS (both-sides involution), T5 setprio.
__global__ __launch_bounds__(512, 2) void gemm256(
    const unsigned short* __restrict__ A, const unsigned short* __restrict__ Bt,
    unsigned short* __restrict__ out, int M, int N, int K)
{
  extern __shared__ char lds[];    // [A: 2buf x 2half x 128 x 64][B: same] = 131072 B
  const int t = threadIdx.x;
  const int wave = t >> 6, lane = t & 63;
  const int wr = wave >> 2, wc = wave & 3;
  const int la = lane & 15, ls = lane >> 4;

  // T1 bijective XCD swizzle (nwg % 8 == 0), column-major decode
  const int gridY = M >> 8;
  const int q8 = gridDim.x >> 3;
  const int orig = blockIdx.x;
  const int swz = (orig & 7) * q8 + (orig >> 3);
  const int by = swz % gridY;
  const int bx = swz / gridY;
  const int brow = by << 8, bcol = bx << 8;
  const int nT = K >> 6;

  // staging: linear LDS dest (wave-uniform + lane*16), pre-swizzled global src
  const int srr = t >> 3;                              // row within half (0..63) + j*64
  const int ssc = ((t & 7) ^ ((t >> 3) & 7)) << 3;     // swizzled source col (elems)

  auto stageA = [&](int kt, int buf, int hf) {
    const unsigned short* src = A + (size_t)(brow + hf * 128 + srr) * K + kt * 64 + ssc;
    char* dst = lds + buf * 32768 + hf * 16384 + t * 16;
    load16(src, dst);
    load16(src + (size_t)64 * K, dst + 8192);
  };
  auto stageB = [&](int kt, int buf, int hf) {
    const unsigned short* src = Bt + (size_t)(bcol + hf * 128 + srr) * K + kt * 64 + ssc;
    char* dst = lds + 65536 + buf * 32768 + hf * 16384 + t * 16;
    load16(src, dst);
    load16(src + (size_t)64 * K, dst + 8192);
  };

  // prologue: tile0 all 4 halves + tile1 A halves; wait all but last 2 halves
  const int t1 = (nT > 1) ? 1 : 0;
  stageA(0, 0, 0); stageA(0, 0, 1);
  stageB(0, 0, 0); stageB(0, 0, 1);
  stageA(t1, 1, 0); stageA(t1, 1, 1);
  asm volatile("s_waitcnt vmcnt(4)" ::: "memory");
  __builtin_amdgcn_s_barrier();

  f32x4 acc[8][4];
#pragma unroll
  for (int m = 0; m < 8; ++m)
#pragma unroll
    for (int n = 0; n < 4; ++n) acc[m][n] = (f32x4){0.f, 0.f, 0.f, 0.f};

  const int sw = (la & 7) << 4;
  const int c0 = (ls << 4) ^ sw;                       // swizzled k0 byte col

  for (int kt = 0; kt < nT; ++kt) {
    const int buf = kt & 1;
    const int kt1 = (kt + 1 < nT) ? kt + 1 : nT - 1;
    const int kt2 = (kt + 2 < nT) ? kt + 2 : nT - 1;
    const char* ab = lds + buf * 32768 + wr * 16384;
    const char* bb = lds + 65536 + buf * 32768 + (wc >> 1) * 16384;
    const int brb = (wc & 1) * 64;
    bfrag a0[8], a1[8], b0[4], b1[4];

    // ---- P1: read A k0 (8) + B k0 (4); stage B0(kt+1); MFMA m0-3 k0
#pragma unroll
    for (int m = 0; m < 8; ++m)
      a0[m] = *(const bfrag*)(ab + (m * 16 + la) * 128 + c0);
#pragma unroll
    for (int n = 0; n < 4; ++n)
      b0[n] = *(const bfrag*)(bb + (brb + n * 16 + la) * 128 + c0);
    stageB(kt1, buf ^ 1, 0);
    __builtin_amdgcn_s_barrier();
    __builtin_amdgcn_s_setprio(1);
#pragma unroll
    for (int m = 0; m < 4; ++m)
#pragma unroll
      for (int n = 0; n < 4; ++n)
        acc[m][n] = __builtin_amdgcn_mfma_f32_16x16x32_bf16(a0[m], b0[n], acc[m][n], 0, 0, 0);
    __builtin_amdgcn_s_setprio(0);
    __builtin_amdgcn_s_barrier();

    // ---- P2: read A k1 (8); stage B1(kt+1); MFMA m4-7 k0; drain lgkm
#pragma unroll
    for (int m = 0; m < 8; ++m)
      a1[m] = *(const bfrag*)(ab + (m * 16 + la) * 128 + (c0 ^ 64));
    stageB(kt1, buf ^ 1, 1);
    __builtin_amdgcn_s_barrier();
    __builtin_amdgcn_s_setprio(1);
#pragma unroll
    for (int m = 4; m < 8; ++m)
#pragma unroll
      for (int n = 0; n < 4; ++n)
        acc[m][n] = __builtin_amdgcn_mfma_f32_16x16x32_bf16(a0[m], b0[n], acc[m][n], 0, 0, 0);
    __builtin_amdgcn_s_setprio(0);
    asm volatile("s_waitcnt lgkmcnt(0)" ::: "memory");  // A reads done before P3 stage lands
    __builtin_amdgcn_s_barrier();

    // ---- P3: read B k1 (4); stage A0(kt+2) into current buf; MFMA m0-3 k1
#pragma unroll
    for (int n = 0; n < 4; ++n)
      b1[n] = *(const bfrag*)(bb + (brb + n * 16 + la) * 128 + (c0 ^ 64));
    stageA(kt2, buf, 0);
    __builtin_amdgcn_s_barrier();
    __builtin_amdgcn_s_setprio(1);
#pragma unroll
    for (int m = 0; m < 4; ++m)
#pragma unroll
      for (int n = 0; n < 4; ++n)
        acc[m][n] = __builtin_amdgcn_mfma_f32_16x16x32_bf16(a1[m], b1[n], acc[m][n], 0, 0, 0);
    __builtin_amdgcn_s_setprio(0);
    __builtin_amdgcn_s_barrier();

    // ---- P4: stage A1(kt+2); MFMA m4-7 k1; counted vmcnt before barrier
    stageA(kt2, buf, 1);
    __builtin_amdgcn_s_barrier();
    __builtin_amdgcn_s_setprio(1);
#pragma unroll
    for (int m = 4; m < 8; ++m)
#pragma unroll
      for (int n = 0; n < 4; ++n)
        acc[m][n] = __builtin_amdgcn_mfma_f32_16x16x32_bf16(a1[m], b1[n], acc[m][n], 0, 0, 0);
    __builtin_amdgcn_s_setprio(0);
    asm volatile("s_waitcnt vmcnt(4)" ::: "memory");
    __builtin_amdgcn_s_barrier();
  }

  // epilogue: frag (m,n): row = wr*128 + m*16 + ls*4 + r, col = wc*64 + n*16 + la
  const int orow = brow + wr * 128 + ls * 4;
  const int ocol = bcol + wc * 64 + la;
#pragma unroll
  for (int m = 0; m < 8; ++m)
#pragma unroll
    for (int n = 0; n < 4; ++n)
#pragma unroll
      for (int r = 0; r < 4; ++r)
        out[(size_t)(orow + m * 16 + r) * N + (ocol + n * 16)] = f2bf(acc[m][n][r]);
}

// ---------------- 128x128 GEMM (m97 structure) — kept for split-K hc -------
__global__ __launch_bounds__(256) void gemm_bt(
    const unsigned short* __restrict__ A, const unsigned short* __restrict__ Bt,
    void* __restrict__ out, int M, int N, int K, int kPerSlice, int outF32)
{
  __shared__ unsigned short sA[128 * 32];
  __shared__ unsigned short sB[128 * 32];
  const int t = threadIdx.x;
  const int wave = t >> 6, lane = t & 63;
  const int wr = wave >> 1, wc = wave & 1;
  const int brow = blockIdx.y << 7;
  const int bcol = blockIdx.x << 7;
  const int kOff = blockIdx.z * kPerSlice;

  f32x4 acc[4][4];
#pragma unroll
  for (int m = 0; m < 4; m++)
#pragma unroll
    for (int n = 0; n < 4; n++) acc[m][n] = (f32x4){0.f, 0.f, 0.f, 0.f};

  const int srow = t >> 2;
  const int scol = (t & 3) << 3;
  const unsigned short* aSrc = A + (size_t)(brow + srow) * K + kOff + scol;
  const unsigned short* bSrc = Bt + (size_t)(bcol + srow) * K + kOff + scol;
  const size_t rowStep = (size_t)64 * K;
  unsigned short* dA0 = sA + wave * 512;
  unsigned short* dA1 = sA + 2048 + wave * 512;
  unsigned short* dB0 = sB + wave * 512;
  unsigned short* dB1 = sB + 2048 + wave * 512;

  const int la = lane & 15;
  const int lk = (lane >> 4) << 3;
  const int kSteps = kPerSlice >> 5;

  for (int ks = 0; ks < kSteps; ++ks) {
    load16(aSrc, dA0);
    load16(aSrc + rowStep, dA1);
    load16(bSrc, dB0);
    load16(bSrc + rowStep, dB1);
    aSrc += 32; bSrc += 32;
    __syncthreads();
    bfrag aF[4], bF[4];
#pragma unroll
    for (int m = 0; m < 4; m++)
      aF[m] = *(const bfrag*)&sA[(wr * 64 + m * 16 + la) * 32 + lk];
#pragma unroll
    for (int n = 0; n < 4; n++)
      bF[n] = *(const bfrag*)&sB[(wc * 64 + n * 16 + la) * 32 + lk];
#pragma unroll
    for (int m = 0; m < 4; m++)
#pragma unroll
      for (int n = 0; n < 4; n++)
        acc[m][n] = __builtin_amdgcn_mfma_f32_16x16x32_bf16(aF[m], bF[n], acc[m][n], 0, 0, 0);
    __syncthreads();
  }

  const int orow = brow + wr * 64 + (lane >> 4) * 4;
  const int ocol = bcol + wc * 64 + la;
  if (outF32) {
    float* o = (float*)out + (size_t)blockIdx.z * ((size_t)M * N);
#pragma unroll
    for (int m = 0; m < 4; m++) {
      const int rb = orow + m * 16;
#pragma unroll
      for (int n = 0; n < 4; n++) {
        const int cb = ocol + n * 16;
#pragma unroll
        for (int r = 0; r < 4; r++)
          o[(size_t)(rb + r) * N + cb] = acc[m][n][r];
      }
    }
  } else {
    unsigned short* o = (unsigned short*)out;
#pragma unroll
    for (int m = 0; m < 4; m++) {
      const int rb = orow + m * 16;
#pragma unroll
      for (int n = 0; n < 4; n++) {
        const int cb = ocol + n * 16;
#pragma unroll
        for (int r = 0; r < 4; r++)
          o[(size_t)(rb + r) * N + cb] = f2bf(acc[m][n][r]);
      }
    }
  }
}

// ---------------- GRU pointwise + probs ----------------
__global__ __launch_bounds__(256) void gru_pointwise(
    const unsigned short* __restrict__ Gi, const unsigned short* __restrict__ Gh,
    const float* __restrict__ b_ih, const float* __restrict__ b_hh,
    const float* __restrict__ ph, const float* __restrict__ enc,
    const float* __restrict__ W_p, const float* __restrict__ b_p,
    unsigned short* __restrict__ hn, float* __restrict__ probs)
{
  const int bd = blockIdx.x;
  const int b = bd >> 3, d = bd & 7;
  const int t = threadIdx.x;
  const size_t gbase = (size_t)b * NG_ + (size_t)d * G3_;
  const int bbase = d * G3_;
  float partial = 0.f;
#pragma unroll
  for (int i = 0; i < 4; ++i) {
    const int h = t + (i << 8);
    float ir  = bf2f(Gi[gbase + h])        + b_ih[bbase + h];
    float iz  = bf2f(Gi[gbase + 1024 + h]) + b_ih[bbase + 1024 + h];
    float inn = bf2f(Gi[gbase + 2048 + h]) + b_ih[bbase + 2048 + h];
    float hr  = bf2f(Gh[gbase + h])        + b_hh[bbase + h];
    float hz  = bf2f(Gh[gbase + 1024 + h]) + b_hh[bbase + 1024 + h];
    float hnn = bf2f(Gh[gbase + 2048 + h]) + b_hh[bbase + 2048 + h];
    float r = fast_sigmoid(ir + hr);
    float z = fast_sigmoid(iz + hz);
    float nn = fast_tanh(inn + r * hnn);
    float h0 = (h < 512) ? ph[b * 512 + h] : enc[b * 512 + h - 512];
    float hv = (1.f - z) * nn + z * h0;
    hn[(size_t)b * 8192 + d * 1024 + h] = f2bf(hv);
    partial += hv * W_p[d * 1024 + h];
  }
  __shared__ float red[256];
  red[t] = partial;
  __syncthreads();
  for (int s = 128; s > 0; s >>= 1) {
    if (t < s) red[t] += red[t + s];
    __syncthreads();
  }
  if (t == 0) probs[bd] = fast_sigmoid(red[0] + b_p[d]);
}

// ---------------- reduce split-K partials + bias + tanh -> h ----------------
__global__ __launch_bounds__(256) void reduce_h_kernel(
    const float* __restrict__ part, const float* __restrict__ b_h,
    float* __restrict__ hout)
{
  const int idx = blockIdx.x * 256 + threadIdx.x;
  const int kk = idx & 511;
  float s = 0.f;
#pragma unroll
  for (int sl = 0; sl < 8; ++sl) s += part[(size_t)sl * 1048576 + idx];
  float bias = 0.f;
#pragma unroll
  for (int d = 0; d < 8; ++d) bias += b_h[d * 512 + kk];
  hout[idx] = fast_tanh(s + bias);
}

extern "C" void kernel_launch(void* const* d_in, const int* in_sizes, int n_in,
                              void* d_out, int out_size, void* d_ws, size_t ws_size,
                              hipStream_t stream) {
  const float* x   = (const float*)d_in[0];
  const float* ph  = (const float*)d_in[1];
  const float* enc = (const float*)d_in[2];
  const float* Wih = (const float*)d_in[3];
  const float* Whh = (const float*)d_in[4];
  const float* bih = (const float*)d_in[5];
  const float* bhh = (const float*)d_in[6];
  const float* Wp  = (const float*)d_in[7];
  const float* bp  = (const float*)d_in[8];
  const float* Wh  = (const float*)d_in[9];
  const float* bh  = (const float*)d_in[10];
  float* out = (float*)d_out;
  char* ws = (char*)d_ws;

  unsigned short* A1   = (unsigned short*)(ws + 0);
  unsigned short* A2   = (unsigned short*)(ws + 1048576);
  unsigned short* BWih = (unsigned short*)(ws + 5242880);
  unsigned short* BWhh = (unsigned short*)(ws + 17825792);
  unsigned short* BWh  = (unsigned short*)(ws + 68157440);
  unsigned short* Gi   = (unsigned short*)(ws + 76546048);
  unsigned short* Gh   = (unsigned short*)(ws + 177209344);
  unsigned short* hn   = (unsigned short*)(ws + 277872640);
  float*          part = (float*)(ws + 311427072);

  hipFuncSetAttribute((const void*)gemm256,
                      hipFuncAttributeMaxDynamicSharedMemorySize, 131072);

  pack_kernel<<<2048, 256, 0, stream>>>(x, ph, enc, Wih, Whh, Wh,
                                        A1, A2, BWih, BWhh, BWh);

  const int nwg = (NG_ / 256) * (B_ / 256);        // 96*8 = 768, %8==0
  gemm256<<<nwg, 512, 131072, stream>>>(A1, BWih, Gi, B_, NG_, C_);
  gemm256<<<nwg, 512, 131072, stream>>>(A2, BWhh, Gh, B_, NG_, H2_);

  gru_pointwise<<<B_ * D_, 256, 0, stream>>>(Gi, Gh, bih, bhh, ph, enc, Wp, bp,
                                             hn, out + 1048576);

  dim3 g3(HS_ / 128, B_ / 128, 8);
  gemm_bt<<<g3, 256, 0, stream>>>(hn, BWh, part, B_, HS_, 8192, 1024, 1);

  reduce_h_kernel<<<4096, 256, 0, stream>>>(part, bh, out);
}